// Round 1
// baseline (186.791 us; speedup 1.0000x reference)
//
#include <hip/hip_runtime.h>
#include <math.h>

#define HH 128
#define WW 128
#define MAP_ELEMS (HH * WW)   // 16384
#define BLOCK 256
#define ITERS (MAP_ELEMS / 4 / BLOCK)  // 16 float4 per thread

__global__ __launch_bounds__(BLOCK) void spatial_argmax2d_kernel(
    const float* __restrict__ in, float* __restrict__ out) {
    const int map = blockIdx.x;  // b*N + n
    const float* __restrict__ base = in + (size_t)map * MAP_ELEMS;
    const float4* __restrict__ base4 = (const float4*)base;
    const int tid = threadIdx.x;

    float best_v = -INFINITY;
    int best_i = 0x7fffffff;

    // Coalesced strided float4 scan. Per-thread indices increase monotonically
    // across iterations and within the float4, so strict '>' keeps the FIRST
    // occurrence of the max (jnp.argmax semantics).
#pragma unroll
    for (int k = 0; k < ITERS; ++k) {
        const int i4 = k * BLOCK + tid;
        const float4 v = base4[i4];
        const int i0 = i4 * 4;
        if (v.x > best_v) { best_v = v.x; best_i = i0; }
        if (v.y > best_v) { best_v = v.y; best_i = i0 + 1; }
        if (v.z > best_v) { best_v = v.z; best_i = i0 + 2; }
        if (v.w > best_v) { best_v = v.w; best_i = i0 + 3; }
    }

    // 64-lane wave reduction (wavefront = 64 on CDNA).
#pragma unroll
    for (int off = 32; off > 0; off >>= 1) {
        const float v2 = __shfl_down(best_v, off);
        const int   i2 = __shfl_down(best_i, off);
        if (v2 > best_v || (v2 == best_v && i2 < best_i)) {
            best_v = v2; best_i = i2;
        }
    }

    __shared__ float sv[BLOCK / 64];
    __shared__ int   si[BLOCK / 64];
    const int wave = tid >> 6;
    if ((tid & 63) == 0) { sv[wave] = best_v; si[wave] = best_i; }
    __syncthreads();

    if (tid == 0) {
#pragma unroll
        for (int w = 1; w < BLOCK / 64; ++w) {
            if (sv[w] > best_v || (sv[w] == best_v && si[w] < best_i)) {
                best_v = sv[w]; best_i = si[w];
            }
        }
        const int y = best_i >> 7;        // / 128
        const int x = best_i & (WW - 1);  // % 128

        // Replicate padding == clamped neighbor coords.
        const float c = best_v;
        const int xl = (x > 0)      ? x - 1 : 0;
        const int xr = (x < WW - 1) ? x + 1 : WW - 1;
        const int yu = (y > 0)      ? y - 1 : 0;
        const int yd = (y < HH - 1) ? y + 1 : HH - 1;
        const float l = base[y  * WW + xl];
        const float r = base[y  * WW + xr];
        const float u = base[yu * WW + x];
        const float d = base[yd * WW + x];

        const float den_x = l - 2.0f * c + r;
        const float den_y = u - 2.0f * c + d;
        const float dx = (den_x != 0.0f) ? 0.5f * (l - r) / den_x : 0.0f;
        const float dy = (den_y != 0.0f) ? 0.5f * (u - d) / den_y : 0.0f;

        out[map * 2 + 0] = (float)x + dx;
        out[map * 2 + 1] = (float)y + dy;
    }
}

extern "C" void kernel_launch(void* const* d_in, const int* in_sizes, int n_in,
                              void* d_out, int out_size, void* d_ws, size_t ws_size,
                              hipStream_t stream) {
    const float* in = (const float*)d_in[0];
    float* out = (float*)d_out;
    const int n_maps = in_sizes[0] / MAP_ELEMS;  // B*N = 2048
    spatial_argmax2d_kernel<<<n_maps, BLOCK, 0, stream>>>(in, out);
}